// Round 1
// baseline (8821.952 us; speedup 1.0000x reference)
//
#include <hip/hip_runtime.h>

constexpr float LN_EPS = 1e-5f;

// ---------------------------------------------------------------- degrees
__global__ void deg_kernel(const int* __restrict__ src, const int* __restrict__ dst,
                           float* __restrict__ deg_o, float* __restrict__ deg_i, int E) {
  int i = blockIdx.x * blockDim.x + threadIdx.x;
  const int stride = gridDim.x * blockDim.x;
  for (; i < E; i += stride) {
    atomicAdd(&deg_o[src[i]], 1.0f);
    atomicAdd(&deg_i[dst[i]], 1.0f);
  }
}

__global__ void norm_kernel(float* __restrict__ deg_o, float* __restrict__ deg_i, int N) {
  int i = blockIdx.x * blockDim.x + threadIdx.x;
  if (i < N) {
    deg_o[i] = rsqrtf(fmaxf(deg_o[i], 1.0f));
    deg_i[i] = rsqrtf(fmaxf(deg_i[i], 1.0f));
  }
}

// ------------------------------------------------- edge scatter (d = 128)
// 32 threads per edge; each thread gathers float4 from h[src] and does 4
// global fp32 atomic adds into agg[dst]. coef = norm_o[src]*norm_i[dst]
// (fuses the trailing *norm_i pass of the reference).
__global__ __launch_bounds__(256) void scatter128(
    const float* __restrict__ h, const int* __restrict__ src,
    const int* __restrict__ dst, const float* __restrict__ no,
    const float* __restrict__ ni, float* __restrict__ agg, int E) {
  int t = blockIdx.x * blockDim.x + threadIdx.x;
  int e = t >> 5;
  if (e >= E) return;
  int c = (t & 31) << 2;
  int u = src[e], v = dst[e];
  float coef = no[u] * ni[v];
  float4 hv = *reinterpret_cast<const float4*>(h + (size_t)u * 128 + c);
  float* a = agg + (size_t)v * 128 + c;
  atomicAdd(a + 0, hv.x * coef);
  atomicAdd(a + 1, hv.y * coef);
  atomicAdd(a + 2, hv.z * coef);
  atomicAdd(a + 3, hv.w * coef);
}

// -------------------------------- fused matmul(128x128) + bias + LN + ReLU
// W resident in LDS (64 KB). 256 threads = 2 row-groups of 128 threads.
// Grid-stride over rows; LN reduce = wave shfl_xor + LDS cross-wave combine.
__global__ __launch_bounds__(256) void mm_ln_relu(
    const float* __restrict__ A, const float* __restrict__ W,
    const float* __restrict__ b, const float* __restrict__ g,
    const float* __restrict__ be, float* __restrict__ out, int N) {
  __shared__ float Wl[128 * 128];
  __shared__ float rb[2][128];
  __shared__ float shs[4], shq[4];
  for (int i = threadIdx.x; i < 128 * 128; i += 256) Wl[i] = W[i];
  const int grp = threadIdx.x >> 7;   // 0..1
  const int col = threadIdx.x & 127;  // 0..127
  const int wid = threadIdx.x >> 6;   // 0..3
  const float bc = b[col], gc = g[col], bec = be[col];
  __syncthreads();
  const int rpi = gridDim.x * 2;
  const int iters = (N + rpi - 1) / rpi;
  int row = blockIdx.x * 2 + grp;
  for (int it = 0; it < iters; ++it, row += rpi) {
    const bool active = row < N;
    if (active) rb[grp][col] = A[(size_t)row * 128 + col];
    __syncthreads();
    float acc = 0.0f;
    if (active) {
#pragma unroll 16
      for (int k = 0; k < 128; ++k)
        acc = fmaf(rb[grp][k], Wl[(k << 7) + col], acc);
      acc += bc;
    }
    // LN statistics over the 128 cols of this row (2 waves)
    float s = acc, q = acc * acc;
    for (int off = 32; off > 0; off >>= 1) {
      s += __shfl_xor(s, off);
      q += __shfl_xor(q, off);
    }
    if ((threadIdx.x & 63) == 0) { shs[wid] = s; shq[wid] = q; }
    __syncthreads();
    if (active) {
      float S = shs[grp * 2] + shs[grp * 2 + 1];
      float Q = shq[grp * 2] + shq[grp * 2 + 1];
      float mu = S * (1.0f / 128.0f);
      float var = Q * (1.0f / 128.0f) - mu * mu;
      float v = (acc - mu) * rsqrtf(var + LN_EPS) * gc + bec;
      out[(size_t)row * 128 + col] = fmaxf(v, 0.0f);
    }
  }
}

// ------------------------------------- final matmul(128x64) + bias -> out
__global__ __launch_bounds__(256) void mm_final(
    const float* __restrict__ A, const float* __restrict__ W,
    const float* __restrict__ b, float* __restrict__ out, int N) {
  __shared__ float Wl[128 * 64];
  __shared__ float rb[4][128];
  for (int i = threadIdx.x; i < 128 * 64; i += 256) Wl[i] = W[i];
  const int grp = threadIdx.x >> 6;  // 0..3
  const int col = threadIdx.x & 63;  // 0..63
  const float bc = b[col];
  __syncthreads();
  const int rpi = gridDim.x * 4;
  const int iters = (N + rpi - 1) / rpi;
  int row = blockIdx.x * 4 + grp;
  for (int it = 0; it < iters; ++it, row += rpi) {
    const bool active = row < N;
    if (active) {
      rb[grp][col] = A[(size_t)row * 128 + col];
      rb[grp][col + 64] = A[(size_t)row * 128 + col + 64];
    }
    __syncthreads();
    if (active) {
      float acc = 0.0f;
#pragma unroll 16
      for (int k = 0; k < 128; ++k)
        acc = fmaf(rb[grp][k], Wl[(k << 6) + col], acc);
      out[(size_t)row * 64 + col] = acc + bc;
    }
    __syncthreads();
  }
}

extern "C" void kernel_launch(void* const* d_in, const int* in_sizes, int n_in,
                              void* d_out, int out_size, void* d_ws, size_t ws_size,
                              hipStream_t stream) {
  const float* feats = (const float*)d_in[0];
  const int*   src   = (const int*)d_in[1];
  const int*   dst   = (const int*)d_in[2];
  const float* W0    = (const float*)d_in[3];
  const float* b0    = (const float*)d_in[4];
  const float* g0    = (const float*)d_in[5];
  const float* be0   = (const float*)d_in[6];
  const float* W1    = (const float*)d_in[7];
  const float* b1    = (const float*)d_in[8];
  const float* g1    = (const float*)d_in[9];
  const float* be1   = (const float*)d_in[10];
  const float* W2    = (const float*)d_in[11];
  const float* b2    = (const float*)d_in[12];
  float* out = (float*)d_out;

  const int n = in_sizes[0] / 128;  // 100000
  const int e = in_sizes[1];        // 1600000

  // workspace layout
  float* deg_o = (float*)d_ws;                 // n  (becomes norm_o)
  float* deg_i = deg_o + n;                    // n  (becomes norm_i)
  float* agg   = deg_i + n;                    // n*128
  float* h     = agg + (size_t)n * 128;        // n*128

  const size_t aggBytes = (size_t)n * 128 * sizeof(float);

  // degrees + norms
  hipMemsetAsync(deg_o, 0, 2 * (size_t)n * sizeof(float), stream);
  deg_kernel<<<2048, 256, 0, stream>>>(src, dst, deg_o, deg_i, e);
  norm_kernel<<<(n + 255) / 256, 256, 0, stream>>>(deg_o, deg_i, n);

  const int scatterBlocks = (e + 7) / 8;  // 32 threads/edge, 8 edges/block

  // layer 0
  hipMemsetAsync(agg, 0, aggBytes, stream);
  scatter128<<<scatterBlocks, 256, 0, stream>>>(feats, src, dst, deg_o, deg_i, agg, e);
  mm_ln_relu<<<1024, 256, 0, stream>>>(agg, W0, b0, g0, be0, h, n);

  // layer 1
  hipMemsetAsync(agg, 0, aggBytes, stream);
  scatter128<<<scatterBlocks, 256, 0, stream>>>(h, src, dst, deg_o, deg_i, agg, e);
  mm_ln_relu<<<1024, 256, 0, stream>>>(agg, W1, b1, g1, be1, h, n);

  // final layer
  hipMemsetAsync(agg, 0, aggBytes, stream);
  scatter128<<<scatterBlocks, 256, 0, stream>>>(h, src, dst, deg_o, deg_i, agg, e);
  mm_final<<<1024, 256, 0, stream>>>(agg, W2, b2, out, n);
}

// Round 2
// 1323.908 us; speedup vs baseline: 6.6636x; 6.6636x over previous
//
#include <hip/hip_runtime.h>

constexpr float LN_EPS = 1e-5f;

// ============================== CSR build =================================
__global__ void deg_int_kernel(const int* __restrict__ src, const int* __restrict__ dst,
                               int* __restrict__ dgo, int* __restrict__ dgi, int E) {
  int i = blockIdx.x * blockDim.x + threadIdx.x;
  const int stride = gridDim.x * blockDim.x;
  for (; i < E; i += stride) {
    atomicAdd(&dgo[src[i]], 1);
    atomicAdd(&dgi[dst[i]], 1);
  }
}

__global__ void norm_from_int_kernel(const int* __restrict__ dgo, const int* __restrict__ dgi,
                                     float* __restrict__ no, float* __restrict__ ni, int N) {
  int i = blockIdx.x * blockDim.x + threadIdx.x;
  if (i < N) {
    no[i] = rsqrtf(fmaxf((float)dgo[i], 1.0f));
    ni[i] = rsqrtf(fmaxf((float)dgi[i], 1.0f));
  }
}

// one-block exclusive scan over N (<= 1024*chunk) elements
__global__ __launch_bounds__(1024) void scan_kernel(const int* __restrict__ deg,
                                                    int* __restrict__ row_start, int N, int E) {
  __shared__ int psum[1024];
  const int t = threadIdx.x;
  const int chunk = (N + 1023) >> 10;
  const int lo = t * chunk;
  const int hi = min(lo + chunk, N);
  int s = 0;
  for (int i = lo; i < hi; ++i) s += deg[i];
  psum[t] = s;
  __syncthreads();
  for (int off = 1; off < 1024; off <<= 1) {
    int x = (t >= off) ? psum[t - off] : 0;
    __syncthreads();
    psum[t] += x;
    __syncthreads();
  }
  int run = psum[t] - s;  // exclusive prefix of this chunk
  for (int i = lo; i < hi; ++i) { row_start[i] = run; run += deg[i]; }
  if (t == 0) row_start[N] = E;
}

__global__ void fill_kernel(const int* __restrict__ src, const int* __restrict__ dst,
                            const int* __restrict__ row_start, int* __restrict__ cursor,
                            int* __restrict__ edge_src, int E) {
  int i = blockIdx.x * blockDim.x + threadIdx.x;
  const int stride = gridDim.x * blockDim.x;
  for (; i < E; i += stride) {
    int v = dst[i];
    int pos = row_start[v] + atomicAdd(&cursor[v], 1);
    edge_src[pos] = src[i];
  }
}

// ===================== per-node gather aggregation (d=128) ================
// One wave per node; lane l owns cols [2l, 2l+1]. agg[v] = ni[v] *
// sum_{u in in(v)} no[u] * h[u].  No atomics, overwrites agg (no memset).
__global__ __launch_bounds__(256) void gather_agg(
    const float* __restrict__ h, const int* __restrict__ row_start,
    const int* __restrict__ edge_src, const float* __restrict__ no,
    const float* __restrict__ ni, float* __restrict__ agg, int N) {
  const int v = blockIdx.x * 4 + (threadIdx.x >> 6);
  if (v >= N) return;
  const int lane = threadIdx.x & 63;
  const int s = row_start[v];
  const int e = row_start[v + 1];
  float2 acc0 = {0.0f, 0.0f}, acc1 = {0.0f, 0.0f};
  int j = s;
  for (; j + 2 <= e; j += 2) {
    int u0 = edge_src[j];
    int u1 = edge_src[j + 1];
    float w0 = no[u0], w1 = no[u1];
    float2 a = *reinterpret_cast<const float2*>(h + (size_t)u0 * 128 + 2 * lane);
    float2 b = *reinterpret_cast<const float2*>(h + (size_t)u1 * 128 + 2 * lane);
    acc0.x = fmaf(a.x, w0, acc0.x);
    acc0.y = fmaf(a.y, w0, acc0.y);
    acc1.x = fmaf(b.x, w1, acc1.x);
    acc1.y = fmaf(b.y, w1, acc1.y);
  }
  if (j < e) {
    int u0 = edge_src[j];
    float w0 = no[u0];
    float2 a = *reinterpret_cast<const float2*>(h + (size_t)u0 * 128 + 2 * lane);
    acc0.x = fmaf(a.x, w0, acc0.x);
    acc0.y = fmaf(a.y, w0, acc0.y);
  }
  const float niv = ni[v];
  float2 r = {(acc0.x + acc1.x) * niv, (acc0.y + acc1.y) * niv};
  *reinterpret_cast<float2*>(agg + (size_t)v * 128 + 2 * lane) = r;
}

// ============== fallback atomic scatter (if workspace too small) ==========
__global__ void deg_kernel_f(const int* __restrict__ src, const int* __restrict__ dst,
                             float* __restrict__ deg_o, float* __restrict__ deg_i, int E) {
  int i = blockIdx.x * blockDim.x + threadIdx.x;
  const int stride = gridDim.x * blockDim.x;
  for (; i < E; i += stride) {
    atomicAdd(&deg_o[src[i]], 1.0f);
    atomicAdd(&deg_i[dst[i]], 1.0f);
  }
}

__global__ void norm_kernel_f(float* __restrict__ deg_o, float* __restrict__ deg_i, int N) {
  int i = blockIdx.x * blockDim.x + threadIdx.x;
  if (i < N) {
    deg_o[i] = rsqrtf(fmaxf(deg_o[i], 1.0f));
    deg_i[i] = rsqrtf(fmaxf(deg_i[i], 1.0f));
  }
}

__global__ __launch_bounds__(256) void scatter128(
    const float* __restrict__ h, const int* __restrict__ src,
    const int* __restrict__ dst, const float* __restrict__ no,
    const float* __restrict__ ni, float* __restrict__ agg, int E) {
  int t = blockIdx.x * blockDim.x + threadIdx.x;
  int e = t >> 5;
  if (e >= E) return;
  int c = (t & 31) << 2;
  int u = src[e], v = dst[e];
  float coef = no[u] * ni[v];
  float4 hv = *reinterpret_cast<const float4*>(h + (size_t)u * 128 + c);
  float* a = agg + (size_t)v * 128 + c;
  atomicAdd(a + 0, hv.x * coef);
  atomicAdd(a + 1, hv.y * coef);
  atomicAdd(a + 2, hv.z * coef);
  atomicAdd(a + 3, hv.w * coef);
}

// ============== fused matmul(128x128) + bias + LN + ReLU ==================
__global__ __launch_bounds__(256) void mm_ln_relu(
    const float* __restrict__ A, const float* __restrict__ W,
    const float* __restrict__ b, const float* __restrict__ g,
    const float* __restrict__ be, float* __restrict__ out, int N) {
  __shared__ float Wl[128 * 128];
  __shared__ float rb[2][128];
  __shared__ float shs[4], shq[4];
  for (int i = threadIdx.x; i < 128 * 128; i += 256) Wl[i] = W[i];
  const int grp = threadIdx.x >> 7;   // 0..1
  const int col = threadIdx.x & 127;  // 0..127
  const int wid = threadIdx.x >> 6;   // 0..3
  const float bc = b[col], gc = g[col], bec = be[col];
  __syncthreads();
  const int rpi = gridDim.x * 2;
  const int iters = (N + rpi - 1) / rpi;
  int row = blockIdx.x * 2 + grp;
  for (int it = 0; it < iters; ++it, row += rpi) {
    const bool active = row < N;
    if (active) rb[grp][col] = A[(size_t)row * 128 + col];
    __syncthreads();
    float acc = 0.0f;
    if (active) {
#pragma unroll 16
      for (int k = 0; k < 128; ++k)
        acc = fmaf(rb[grp][k], Wl[(k << 7) + col], acc);
      acc += bc;
    }
    float s = acc, q = acc * acc;
    for (int off = 32; off > 0; off >>= 1) {
      s += __shfl_xor(s, off);
      q += __shfl_xor(q, off);
    }
    if ((threadIdx.x & 63) == 0) { shs[wid] = s; shq[wid] = q; }
    __syncthreads();
    if (active) {
      float S = shs[grp * 2] + shs[grp * 2 + 1];
      float Q = shq[grp * 2] + shq[grp * 2 + 1];
      float mu = S * (1.0f / 128.0f);
      float var = Q * (1.0f / 128.0f) - mu * mu;
      float v = (acc - mu) * rsqrtf(var + LN_EPS) * gc + bec;
      out[(size_t)row * 128 + col] = fmaxf(v, 0.0f);
    }
  }
}

// ================= final matmul(128x64) + bias -> out =====================
__global__ __launch_bounds__(256) void mm_final(
    const float* __restrict__ A, const float* __restrict__ W,
    const float* __restrict__ b, float* __restrict__ out, int N) {
  __shared__ float Wl[128 * 64];
  __shared__ float rb[4][128];
  for (int i = threadIdx.x; i < 128 * 64; i += 256) Wl[i] = W[i];
  const int grp = threadIdx.x >> 6;  // 0..3
  const int col = threadIdx.x & 63;  // 0..63
  const float bc = b[col];
  __syncthreads();
  const int rpi = gridDim.x * 4;
  const int iters = (N + rpi - 1) / rpi;
  int row = blockIdx.x * 4 + grp;
  for (int it = 0; it < iters; ++it, row += rpi) {
    const bool active = row < N;
    if (active) {
      rb[grp][col] = A[(size_t)row * 128 + col];
      rb[grp][col + 64] = A[(size_t)row * 128 + col + 64];
    }
    __syncthreads();
    if (active) {
      float acc = 0.0f;
#pragma unroll 16
      for (int k = 0; k < 128; ++k)
        acc = fmaf(rb[grp][k], Wl[(k << 6) + col], acc);
      out[(size_t)row * 64 + col] = acc + bc;
    }
    __syncthreads();
  }
}

extern "C" void kernel_launch(void* const* d_in, const int* in_sizes, int n_in,
                              void* d_out, int out_size, void* d_ws, size_t ws_size,
                              hipStream_t stream) {
  const float* feats = (const float*)d_in[0];
  const int*   src   = (const int*)d_in[1];
  const int*   dst   = (const int*)d_in[2];
  const float* W0    = (const float*)d_in[3];
  const float* b0    = (const float*)d_in[4];
  const float* g0    = (const float*)d_in[5];
  const float* be0   = (const float*)d_in[6];
  const float* W1    = (const float*)d_in[7];
  const float* b1    = (const float*)d_in[8];
  const float* g1    = (const float*)d_in[9];
  const float* be1   = (const float*)d_in[10];
  const float* W2    = (const float*)d_in[11];
  const float* b2    = (const float*)d_in[12];
  float* out = (float*)d_out;

  const int n = in_sizes[0] / 128;  // 100000
  const int e = in_sizes[1];        // 1600000

  float* ws = (float*)d_ws;

  // ---- CSR-path workspace layout (4B elements, padded to 16B) ----
  size_t o = 0;
  auto pad4 = [](size_t x) { return (x + 3) & ~(size_t)3; };
  float* norm_o  = ws + o; o = pad4(o + n);
  float* norm_i  = ws + o; o = pad4(o + n);
  int*   dgo     = (int*)(ws + o); o = pad4(o + n);
  int*   dgi     = (int*)(ws + o); o = pad4(o + n);
  int*   row_st  = (int*)(ws + o); o = pad4(o + n + 1);
  int*   cursor  = (int*)(ws + o); o = pad4(o + n);
  int*   edg_src = (int*)(ws + o); o = pad4(o + (size_t)e);
  float* agg     = ws + o; o += (size_t)n * 128;
  float* h       = ws + o; o += (size_t)n * 128;
  const size_t csr_bytes = o * sizeof(float);

  if (ws_size >= csr_bytes) {
    // ---------------- CSR gather path (no fp atomics) ----------------
    hipMemsetAsync(dgo, 0, 2 * (size_t)((n + 3) & ~3) * sizeof(int), stream);
    deg_int_kernel<<<2048, 256, 0, stream>>>(src, dst, dgo, dgi, e);
    norm_from_int_kernel<<<(n + 255) / 256, 256, 0, stream>>>(dgo, dgi, norm_o, norm_i, n);
    scan_kernel<<<1, 1024, 0, stream>>>(dgi, row_st, n, e);
    hipMemsetAsync(cursor, 0, (size_t)n * sizeof(int), stream);
    fill_kernel<<<2048, 256, 0, stream>>>(src, dst, row_st, cursor, edg_src, e);

    const int gblocks = (n + 3) / 4;
    gather_agg<<<gblocks, 256, 0, stream>>>(feats, row_st, edg_src, norm_o, norm_i, agg, n);
    mm_ln_relu<<<1024, 256, 0, stream>>>(agg, W0, b0, g0, be0, h, n);
    gather_agg<<<gblocks, 256, 0, stream>>>(h, row_st, edg_src, norm_o, norm_i, agg, n);
    mm_ln_relu<<<1024, 256, 0, stream>>>(agg, W1, b1, g1, be1, h, n);
    gather_agg<<<gblocks, 256, 0, stream>>>(h, row_st, edg_src, norm_o, norm_i, agg, n);
    mm_final<<<1024, 256, 0, stream>>>(agg, W2, b2, out, n);
  } else {
    // ---------------- fallback: previous atomic-scatter path ----------------
    float* deg_o = ws;
    float* deg_i = deg_o + n;
    float* agg2  = deg_i + n;
    float* h2    = agg2 + (size_t)n * 128;
    const size_t aggBytes = (size_t)n * 128 * sizeof(float);

    hipMemsetAsync(deg_o, 0, 2 * (size_t)n * sizeof(float), stream);
    deg_kernel_f<<<2048, 256, 0, stream>>>(src, dst, deg_o, deg_i, e);
    norm_kernel_f<<<(n + 255) / 256, 256, 0, stream>>>(deg_o, deg_i, n);

    const int scatterBlocks = (e + 7) / 8;
    hipMemsetAsync(agg2, 0, aggBytes, stream);
    scatter128<<<scatterBlocks, 256, 0, stream>>>(feats, src, dst, deg_o, deg_i, agg2, e);
    mm_ln_relu<<<1024, 256, 0, stream>>>(agg2, W0, b0, g0, be0, h2, n);
    hipMemsetAsync(agg2, 0, aggBytes, stream);
    scatter128<<<scatterBlocks, 256, 0, stream>>>(h2, src, dst, deg_o, deg_i, agg2, e);
    mm_ln_relu<<<1024, 256, 0, stream>>>(agg2, W1, b1, g1, be1, h2, n);
    hipMemsetAsync(agg2, 0, aggBytes, stream);
    scatter128<<<scatterBlocks, 256, 0, stream>>>(h2, src, dst, deg_o, deg_i, agg2, e);
    mm_final<<<1024, 256, 0, stream>>>(agg2, W2, b2, out, n);
  }
}

// Round 3
// 816.527 us; speedup vs baseline: 10.8042x; 1.6214x over previous
//
#include <hip/hip_runtime.h>

constexpr float LN_EPS = 1e-5f;

typedef __bf16 bf16x8 __attribute__((ext_vector_type(8)));
typedef float f32x4 __attribute__((ext_vector_type(4)));

__device__ __forceinline__ unsigned short f2bf(float f) {
  unsigned int u = __float_as_uint(f);
  u = (u + 0x7fffu + ((u >> 16) & 1u)) >> 16;  // RNE
  return (unsigned short)u;
}
__device__ __forceinline__ float bflo(unsigned int p) { return __uint_as_float(p << 16); }
__device__ __forceinline__ float bfhi(unsigned int p) { return __uint_as_float(p & 0xffff0000u); }

// ============================== CSR build =================================
__global__ void deg_int_kernel(const int* __restrict__ src, const int* __restrict__ dst,
                               int* __restrict__ dgo, int* __restrict__ dgi, int E) {
  int i = blockIdx.x * blockDim.x + threadIdx.x;
  const int stride = gridDim.x * blockDim.x;
  for (; i < E; i += stride) {
    atomicAdd(&dgo[src[i]], 1);
    atomicAdd(&dgi[dst[i]], 1);
  }
}

__global__ void norm_from_int_kernel(const int* __restrict__ dgo, const int* __restrict__ dgi,
                                     float* __restrict__ no, float* __restrict__ ni, int N) {
  int i = blockIdx.x * blockDim.x + threadIdx.x;
  if (i < N) {
    no[i] = rsqrtf(fmaxf((float)dgo[i], 1.0f));
    ni[i] = rsqrtf(fmaxf((float)dgi[i], 1.0f));
  }
}

__global__ __launch_bounds__(1024) void scan_kernel(const int* __restrict__ deg,
                                                    int* __restrict__ row_start, int N, int E) {
  __shared__ int psum[1024];
  const int t = threadIdx.x;
  const int chunk = (N + 1023) >> 10;
  const int lo = t * chunk;
  const int hi = min(lo + chunk, N);
  int s = 0;
  for (int i = lo; i < hi; ++i) s += deg[i];
  psum[t] = s;
  __syncthreads();
  for (int off = 1; off < 1024; off <<= 1) {
    int x = (t >= off) ? psum[t - off] : 0;
    __syncthreads();
    psum[t] += x;
    __syncthreads();
  }
  int run = psum[t] - s;
  for (int i = lo; i < hi; ++i) { row_start[i] = run; run += deg[i]; }
  if (t == 0) row_start[N] = E;
}

__global__ void fill_kernel(const int* __restrict__ src, const int* __restrict__ dst,
                            const int* __restrict__ row_start, int* __restrict__ cursor,
                            int* __restrict__ edge_src, int E) {
  int i = blockIdx.x * blockDim.x + threadIdx.x;
  const int stride = gridDim.x * blockDim.x;
  for (; i < E; i += stride) {
    int v = dst[i];
    int pos = row_start[v] + atomicAdd(&cursor[v], 1);
    edge_src[pos] = src[i];
  }
}

// ===================== weight transpose + bf16 convert ====================
// W [K][C] f32 -> Wt [C][K] bf16
__global__ void wconv_kernel(const float* __restrict__ W, unsigned short* __restrict__ Wt,
                             int K, int C) {
  int i = blockIdx.x * blockDim.x + threadIdx.x;
  if (i < K * C) {
    int k = i / C, c = i - k * C;
    Wt[c * K + k] = f2bf(W[i]);
  }
}

// ============= feats f32 -> bf16 with norm_o fold: out = no[r]*F[r][c] ====
__global__ __launch_bounds__(256) void featconv_kernel(const float* __restrict__ F,
                                                       const float* __restrict__ no,
                                                       unsigned short* __restrict__ out, int N) {
  int row = blockIdx.x * 8 + (threadIdx.x >> 5);
  if (row >= N) return;
  int c = (threadIdx.x & 31) * 4;
  float4 v = *reinterpret_cast<const float4*>(F + (size_t)row * 128 + c);
  float nof = no[row];
  unsigned int lo = (unsigned int)f2bf(v.x * nof) | ((unsigned int)f2bf(v.y * nof) << 16);
  unsigned int hi = (unsigned int)f2bf(v.z * nof) | ((unsigned int)f2bf(v.w * nof) << 16);
  uint2 p = {lo, hi};
  *reinterpret_cast<uint2*>(out + (size_t)row * 128 + c) = p;
}

// ================== per-node gather aggregation (bf16) ====================
// agg[v] = bf16( ni[v] * sum_{u in in(v)} h'[u] )   (no[u] pre-folded in h')
__global__ __launch_bounds__(256) void gather_agg_b(
    const unsigned short* __restrict__ hB, const int* __restrict__ row_start,
    const int* __restrict__ edge_src, const float* __restrict__ ni,
    unsigned short* __restrict__ aggB, int N) {
  const int v = blockIdx.x * 4 + (threadIdx.x >> 6);
  if (v >= N) return;
  const int lane = threadIdx.x & 63;
  const int s = row_start[v];
  const int e = row_start[v + 1];
  float a0 = 0.f, a1 = 0.f, b0 = 0.f, b1 = 0.f;
  int j = s;
  for (; j + 2 <= e; j += 2) {
    int u0 = edge_src[j];
    int u1 = edge_src[j + 1];
    unsigned int p0 = *reinterpret_cast<const unsigned int*>(hB + (size_t)u0 * 128 + 2 * lane);
    unsigned int p1 = *reinterpret_cast<const unsigned int*>(hB + (size_t)u1 * 128 + 2 * lane);
    a0 += bflo(p0); a1 += bfhi(p0);
    b0 += bflo(p1); b1 += bfhi(p1);
  }
  if (j < e) {
    unsigned int p0 = *reinterpret_cast<const unsigned int*>(hB + (size_t)edge_src[j] * 128 + 2 * lane);
    a0 += bflo(p0); a1 += bfhi(p0);
  }
  const float niv = ni[v];
  a0 = (a0 + b0) * niv;
  a1 = (a1 + b1) * niv;
  unsigned int po = (unsigned int)f2bf(a0) | ((unsigned int)f2bf(a1) << 16);
  *reinterpret_cast<unsigned int*>(aggB + (size_t)v * 128 + 2 * lane) = po;
}

// ====== MFMA matmul [N,128]x[128,128] + bias + LN + ReLU + no-fold ========
// A row-major bf16, Wt col-major bf16 (Wt[c][k]). 32 rows/block, 4 waves:
// wave w: row-tile rt=w&1 (16 rows), col-half ch=w>>1 (64 cols = 4 MFMA tiles).
__global__ __launch_bounds__(256) void mm_mfma_ln(
    const unsigned short* __restrict__ A, const unsigned short* __restrict__ Wt,
    const float* __restrict__ b, const float* __restrict__ g,
    const float* __restrict__ be, const float* __restrict__ no,
    unsigned short* __restrict__ out, int N) {
  __shared__ float sS[2][2][16];
  __shared__ float sQ[2][2][16];
  __shared__ float sNo[32];
  const int rbase = blockIdx.x * 32;
  const int w = threadIdx.x >> 6;
  const int l = threadIdx.x & 63;
  const int rt = w & 1, ch = w >> 1;
  if (threadIdx.x < 32) sNo[threadIdx.x] = no[min(rbase + (int)threadIdx.x, N - 1)];
  const int arow = min(rbase + rt * 16 + (l & 15), N - 1);
  const int kof = (l >> 4) * 8;

  bf16x8 af[4];
  const unsigned short* ap = A + (size_t)arow * 128 + kof;
#pragma unroll
  for (int kk = 0; kk < 4; ++kk)
    af[kk] = *reinterpret_cast<const bf16x8*>(ap + kk * 32);

  f32x4 acc[4] = {};
#pragma unroll
  for (int ct = 0; ct < 4; ++ct) {
    const int ccol = ch * 64 + ct * 16 + (l & 15);
    const unsigned short* bp = Wt + (size_t)ccol * 128 + kof;
#pragma unroll
    for (int kk = 0; kk < 4; ++kk) {
      bf16x8 bfr = *reinterpret_cast<const bf16x8*>(bp + kk * 32);
      acc[ct] = __builtin_amdgcn_mfma_f32_16x16x32_bf16(af[kk], bfr, acc[ct], 0, 0, 0);
    }
  }

  // bias + LN stats (rows (l>>4)*4+j of this tile, col = ccol)
  float s[4] = {0.f, 0.f, 0.f, 0.f}, q[4] = {0.f, 0.f, 0.f, 0.f};
#pragma unroll
  for (int ct = 0; ct < 4; ++ct) {
    const float bc = b[ch * 64 + ct * 16 + (l & 15)];
#pragma unroll
    for (int j = 0; j < 4; ++j) {
      float v = acc[ct][j] + bc;
      acc[ct][j] = v;
      s[j] += v;
      q[j] += v * v;
    }
  }
#pragma unroll
  for (int j = 0; j < 4; ++j) {
#pragma unroll
    for (int off = 1; off < 16; off <<= 1) {
      s[j] += __shfl_xor(s[j], off);
      q[j] += __shfl_xor(q[j], off);
    }
  }
  const int grp = l >> 4;
  if ((l & 15) == 0) {
#pragma unroll
    for (int j = 0; j < 4; ++j) {
      sS[rt][ch][grp * 4 + j] = s[j];
      sQ[rt][ch][grp * 4 + j] = q[j];
    }
  }
  __syncthreads();

#pragma unroll
  for (int j = 0; j < 4; ++j) {
    const int r = grp * 4 + j;
    const int row = rbase + rt * 16 + r;
    float S = sS[rt][0][r] + sS[rt][1][r];
    float Q = sQ[rt][0][r] + sQ[rt][1][r];
    float mu = S * (1.f / 128.f);
    float rstd = rsqrtf(fmaxf(Q * (1.f / 128.f) - mu * mu, 0.f) + LN_EPS);
    float nof = sNo[rt * 16 + r];
    if (row < N) {
#pragma unroll
      for (int ct = 0; ct < 4; ++ct) {
        const int ccol = ch * 64 + ct * 16 + (l & 15);
        float y = (acc[ct][j] - mu) * rstd * g[ccol] + be[ccol];
        y = fmaxf(y, 0.f) * nof;
        out[(size_t)row * 128 + ccol] = f2bf(y);
      }
    }
  }
}

// ============ final MFMA matmul [N,128]x[128,64] + bias -> f32 out ========
__global__ __launch_bounds__(256) void mm_final_mfma(
    const unsigned short* __restrict__ A, const unsigned short* __restrict__ Wt,
    const float* __restrict__ b, float* __restrict__ out, int N) {
  const int rbase = blockIdx.x * 32;
  const int w = threadIdx.x >> 6;
  const int l = threadIdx.x & 63;
  const int rt = w & 1, ch = w >> 1;  // ch: 32-col half
  const int arow = min(rbase + rt * 16 + (l & 15), N - 1);
  const int kof = (l >> 4) * 8;

  bf16x8 af[4];
  const unsigned short* ap = A + (size_t)arow * 128 + kof;
#pragma unroll
  for (int kk = 0; kk < 4; ++kk)
    af[kk] = *reinterpret_cast<const bf16x8*>(ap + kk * 32);

  f32x4 acc[2] = {};
#pragma unroll
  for (int ct = 0; ct < 2; ++ct) {
    const int ccol = ch * 32 + ct * 16 + (l & 15);
    const unsigned short* bp = Wt + (size_t)ccol * 128 + kof;
#pragma unroll
    for (int kk = 0; kk < 4; ++kk) {
      bf16x8 bfr = *reinterpret_cast<const bf16x8*>(bp + kk * 32);
      acc[ct] = __builtin_amdgcn_mfma_f32_16x16x32_bf16(af[kk], bfr, acc[ct], 0, 0, 0);
    }
  }
  const int grp = l >> 4;
#pragma unroll
  for (int ct = 0; ct < 2; ++ct) {
    const int ccol = ch * 32 + ct * 16 + (l & 15);
    const float bc = b[ccol];
#pragma unroll
    for (int j = 0; j < 4; ++j) {
      const int row = rbase + rt * 16 + grp * 4 + j;
      if (row < N) out[(size_t)row * 64 + ccol] = acc[ct][j] + bc;
    }
  }
}

extern "C" void kernel_launch(void* const* d_in, const int* in_sizes, int n_in,
                              void* d_out, int out_size, void* d_ws, size_t ws_size,
                              hipStream_t stream) {
  const float* feats = (const float*)d_in[0];
  const int*   src   = (const int*)d_in[1];
  const int*   dst   = (const int*)d_in[2];
  const float* W0    = (const float*)d_in[3];
  const float* b0    = (const float*)d_in[4];
  const float* g0    = (const float*)d_in[5];
  const float* be0   = (const float*)d_in[6];
  const float* W1    = (const float*)d_in[7];
  const float* b1    = (const float*)d_in[8];
  const float* g1    = (const float*)d_in[9];
  const float* be1   = (const float*)d_in[10];
  const float* W2    = (const float*)d_in[11];
  const float* b2    = (const float*)d_in[12];
  float* out = (float*)d_out;

  const int n = in_sizes[0] / 128;  // 100000
  const int e = in_sizes[1];        // 1600000

  float* ws = (float*)d_ws;
  auto pad4 = [](size_t x) { return (x + 3) & ~(size_t)3; };
  size_t o = 0;
  float* norm_o  = ws + o; o = pad4(o + n);
  float* norm_i  = ws + o; o = pad4(o + n);
  int*   dgo     = (int*)(ws + o); o = pad4(o + n);
  int*   dgi     = (int*)(ws + o); o = pad4(o + n);
  int*   row_st  = (int*)(ws + o); o = pad4(o + n + 1);
  int*   cursor  = (int*)(ws + o); o = pad4(o + n);
  int*   edg_src = (int*)(ws + o); o = pad4(o + (size_t)e);
  unsigned short* featB = (unsigned short*)(ws + o); o = pad4(o + (size_t)n * 64);
  unsigned short* aggB  = (unsigned short*)(ws + o); o = pad4(o + (size_t)n * 64);
  unsigned short* hB    = (unsigned short*)(ws + o); o = pad4(o + (size_t)n * 64);
  unsigned short* Wt0   = (unsigned short*)(ws + o); o = pad4(o + 128 * 128 / 2);
  unsigned short* Wt1   = (unsigned short*)(ws + o); o = pad4(o + 128 * 128 / 2);
  unsigned short* Wt2   = (unsigned short*)(ws + o); o = pad4(o + 128 * 64 / 2);

  // ---- CSR build ----
  hipMemsetAsync(dgo, 0, 2 * (size_t)pad4(n) * sizeof(int), stream);
  deg_int_kernel<<<2048, 256, 0, stream>>>(src, dst, dgo, dgi, e);
  norm_from_int_kernel<<<(n + 255) / 256, 256, 0, stream>>>(dgo, dgi, norm_o, norm_i, n);
  scan_kernel<<<1, 1024, 0, stream>>>(dgi, row_st, n, e);
  hipMemsetAsync(cursor, 0, (size_t)n * sizeof(int), stream);
  fill_kernel<<<2048, 256, 0, stream>>>(src, dst, row_st, cursor, edg_src, e);

  // ---- weights -> bf16 transposed; feats -> bf16 with no-fold ----
  wconv_kernel<<<(128 * 128 + 255) / 256, 256, 0, stream>>>(W0, Wt0, 128, 128);
  wconv_kernel<<<(128 * 128 + 255) / 256, 256, 0, stream>>>(W1, Wt1, 128, 128);
  wconv_kernel<<<(128 * 64 + 255) / 256, 256, 0, stream>>>(W2, Wt2, 128, 64);
  featconv_kernel<<<(n + 7) / 8, 256, 0, stream>>>(feats, norm_o, featB, n);

  const int gblocks = (n + 3) / 4;
  const int mblocks = (n + 31) / 32;

  // layer 0
  gather_agg_b<<<gblocks, 256, 0, stream>>>(featB, row_st, edg_src, norm_i, aggB, n);
  mm_mfma_ln<<<mblocks, 256, 0, stream>>>(aggB, Wt0, b0, g0, be0, norm_o, hB, n);
  // layer 1
  gather_agg_b<<<gblocks, 256, 0, stream>>>(hB, row_st, edg_src, norm_i, aggB, n);
  mm_mfma_ln<<<mblocks, 256, 0, stream>>>(aggB, Wt1, b1, g1, be1, norm_o, hB, n);
  // final layer
  gather_agg_b<<<gblocks, 256, 0, stream>>>(hB, row_st, edg_src, norm_i, aggB, n);
  mm_final_mfma<<<mblocks, 256, 0, stream>>>(aggB, Wt2, b2, out, n);
}

// Round 4
// 613.664 us; speedup vs baseline: 14.3759x; 1.3306x over previous
//
#include <hip/hip_runtime.h>

constexpr float LN_EPS = 1e-5f;

typedef __bf16 bf16x8 __attribute__((ext_vector_type(8)));
typedef float f32x4 __attribute__((ext_vector_type(4)));

__device__ __forceinline__ unsigned short f2bf(float f) {
  unsigned int u = __float_as_uint(f);
  u = (u + 0x7fffu + ((u >> 16) & 1u)) >> 16;  // RNE
  return (unsigned short)u;
}
__device__ __forceinline__ float bflo(unsigned int p) { return __uint_as_float(p << 16); }
__device__ __forceinline__ float bfhi(unsigned int p) { return __uint_as_float(p & 0xffff0000u); }

// ============================== CSR build =================================
__global__ void deg_int_kernel(const int* __restrict__ src, const int* __restrict__ dst,
                               int* __restrict__ dgo, int* __restrict__ dgi, int E) {
  int i = blockIdx.x * blockDim.x + threadIdx.x;
  const int stride = gridDim.x * blockDim.x;
  for (; i < E; i += stride) {
    atomicAdd(&dgo[src[i]], 1);
    atomicAdd(&dgi[dst[i]], 1);
  }
}

__global__ void norm_from_int_kernel(const int* __restrict__ dgo, const int* __restrict__ dgi,
                                     float* __restrict__ no, float* __restrict__ ni, int N) {
  int i = blockIdx.x * blockDim.x + threadIdx.x;
  if (i < N) {
    no[i] = rsqrtf(fmaxf((float)dgo[i], 1.0f));
    ni[i] = rsqrtf(fmaxf((float)dgi[i], 1.0f));
  }
}

// ---------------- 3-phase multi-block exclusive scan (256 blocks) ---------
__global__ __launch_bounds__(256) void scan_phaseA(const int* __restrict__ deg,
                                                   int* __restrict__ partial, int N) {
  __shared__ int red[256];
  const int chunkB = (N + gridDim.x - 1) / gridDim.x;
  const int lo = blockIdx.x * chunkB;
  const int hi = min(lo + chunkB, N);
  int s = 0;
  for (int i = lo + threadIdx.x; i < hi; i += 256) s += deg[i];
  red[threadIdx.x] = s;
  __syncthreads();
  for (int off = 128; off > 0; off >>= 1) {
    if (threadIdx.x < off) red[threadIdx.x] += red[threadIdx.x + off];
    __syncthreads();
  }
  if (threadIdx.x == 0) partial[blockIdx.x] = red[0];
}

__global__ __launch_bounds__(256) void scan_phaseB(const int* __restrict__ partial,
                                                   int* __restrict__ offsets) {
  __shared__ int psum[256];
  const int t = threadIdx.x;
  const int v = partial[t];
  psum[t] = v;
  __syncthreads();
  for (int off = 1; off < 256; off <<= 1) {
    int x = (t >= off) ? psum[t - off] : 0;
    __syncthreads();
    psum[t] += x;
    __syncthreads();
  }
  offsets[t] = psum[t] - v;  // exclusive
}

__global__ __launch_bounds__(256) void scan_phaseC(const int* __restrict__ deg,
                                                   const int* __restrict__ offsets,
                                                   int* __restrict__ row_start, int N, int E) {
  __shared__ int psum[256];
  const int chunkB = (N + gridDim.x - 1) / gridDim.x;
  const int lo0 = blockIdx.x * chunkB;
  const int hi0 = min(lo0 + chunkB, N);
  const int per = (chunkB + 255) >> 8;
  const int lo = lo0 + threadIdx.x * per;
  const int hi = min(lo + per, hi0);
  int s = 0;
  for (int i = lo; i < hi; ++i) s += deg[i];
  psum[threadIdx.x] = s;
  __syncthreads();
  for (int off = 1; off < 256; off <<= 1) {
    int x = (threadIdx.x >= off) ? psum[threadIdx.x - off] : 0;
    __syncthreads();
    psum[threadIdx.x] += x;
    __syncthreads();
  }
  int run = offsets[blockIdx.x] + psum[threadIdx.x] - s;
  for (int i = lo; i < hi; ++i) { row_start[i] = run; run += deg[i]; }
  if (blockIdx.x == 0 && threadIdx.x == 0) row_start[N] = E;
}

__global__ void fill_kernel(const int* __restrict__ src, const int* __restrict__ dst,
                            const int* __restrict__ row_start, int* __restrict__ cursor,
                            int* __restrict__ edge_src, int E) {
  int i = blockIdx.x * blockDim.x + threadIdx.x;
  const int stride = gridDim.x * blockDim.x;
  for (; i < E; i += stride) {
    int v = dst[i];
    int pos = row_start[v] + atomicAdd(&cursor[v], 1);
    edge_src[pos] = src[i];
  }
}

// ===================== weight transpose + bf16 convert ====================
__global__ void wconv_kernel(const float* __restrict__ W, unsigned short* __restrict__ Wt,
                             int K, int C) {
  int i = blockIdx.x * blockDim.x + threadIdx.x;
  if (i < K * C) {
    int k = i / C, c = i - k * C;
    Wt[c * K + k] = f2bf(W[i]);
  }
}

// ============= feats f32 -> bf16 with norm_o fold: out = no[r]*F[r][c] ====
__global__ __launch_bounds__(256) void featconv_kernel(const float* __restrict__ F,
                                                       const float* __restrict__ no,
                                                       unsigned short* __restrict__ out, int N) {
  int row = blockIdx.x * 8 + (threadIdx.x >> 5);
  if (row >= N) return;
  int c = (threadIdx.x & 31) * 4;
  float4 v = *reinterpret_cast<const float4*>(F + (size_t)row * 128 + c);
  float nof = no[row];
  unsigned int lo = (unsigned int)f2bf(v.x * nof) | ((unsigned int)f2bf(v.y * nof) << 16);
  unsigned int hi = (unsigned int)f2bf(v.z * nof) | ((unsigned int)f2bf(v.w * nof) << 16);
  uint2 p = {lo, hi};
  *reinterpret_cast<uint2*>(out + (size_t)row * 128 + c) = p;
}

// ================== per-node gather aggregation (bf16) ====================
// agg[v] = bf16( ni[v] * sum_{u in in(v)} h'[u] )   (no[u] pre-folded in h')
__global__ __launch_bounds__(256) void gather_agg_b(
    const unsigned short* __restrict__ hB, const int* __restrict__ row_start,
    const int* __restrict__ edge_src, const float* __restrict__ ni,
    unsigned short* __restrict__ aggB, int N) {
  const int v = blockIdx.x * 4 + (threadIdx.x >> 6);
  if (v >= N) return;
  const int lane = threadIdx.x & 63;
  const int s = row_start[v];
  const int e = row_start[v + 1];
  float a0 = 0.f, a1 = 0.f, b0 = 0.f, b1 = 0.f;
  float c0 = 0.f, c1 = 0.f, d0 = 0.f, d1 = 0.f;
  int j = s;
  for (; j + 4 <= e; j += 4) {
    int u0 = edge_src[j], u1 = edge_src[j + 1], u2 = edge_src[j + 2], u3 = edge_src[j + 3];
    unsigned int p0 = *reinterpret_cast<const unsigned int*>(hB + (size_t)u0 * 128 + 2 * lane);
    unsigned int p1 = *reinterpret_cast<const unsigned int*>(hB + (size_t)u1 * 128 + 2 * lane);
    unsigned int p2 = *reinterpret_cast<const unsigned int*>(hB + (size_t)u2 * 128 + 2 * lane);
    unsigned int p3 = *reinterpret_cast<const unsigned int*>(hB + (size_t)u3 * 128 + 2 * lane);
    a0 += bflo(p0); a1 += bfhi(p0);
    b0 += bflo(p1); b1 += bfhi(p1);
    c0 += bflo(p2); c1 += bfhi(p2);
    d0 += bflo(p3); d1 += bfhi(p3);
  }
  for (; j < e; ++j) {
    unsigned int p0 = *reinterpret_cast<const unsigned int*>(hB + (size_t)edge_src[j] * 128 + 2 * lane);
    a0 += bflo(p0); a1 += bfhi(p0);
  }
  const float niv = ni[v];
  a0 = ((a0 + b0) + (c0 + d0)) * niv;
  a1 = ((a1 + b1) + (c1 + d1)) * niv;
  unsigned int po = (unsigned int)f2bf(a0) | ((unsigned int)f2bf(a1) << 16);
  *reinterpret_cast<unsigned int*>(aggB + (size_t)v * 128 + 2 * lane) = po;
}

// ====== MFMA matmul [N,128]x[128,128] + bias + LN + ReLU + no-fold ========
__global__ __launch_bounds__(256) void mm_mfma_ln(
    const unsigned short* __restrict__ A, const unsigned short* __restrict__ Wt,
    const float* __restrict__ b, const float* __restrict__ g,
    const float* __restrict__ be, const float* __restrict__ no,
    unsigned short* __restrict__ out, int N) {
  __shared__ float sS[2][2][16];
  __shared__ float sQ[2][2][16];
  __shared__ float sNo[32];
  const int rbase = blockIdx.x * 32;
  const int w = threadIdx.x >> 6;
  const int l = threadIdx.x & 63;
  const int rt = w & 1, ch = w >> 1;
  if (threadIdx.x < 32) sNo[threadIdx.x] = no[min(rbase + (int)threadIdx.x, N - 1)];
  const int arow = min(rbase + rt * 16 + (l & 15), N - 1);
  const int kof = (l >> 4) * 8;

  bf16x8 af[4];
  const unsigned short* ap = A + (size_t)arow * 128 + kof;
#pragma unroll
  for (int kk = 0; kk < 4; ++kk)
    af[kk] = *reinterpret_cast<const bf16x8*>(ap + kk * 32);

  f32x4 acc[4] = {};
#pragma unroll
  for (int ct = 0; ct < 4; ++ct) {
    const int ccol = ch * 64 + ct * 16 + (l & 15);
    const unsigned short* bp = Wt + (size_t)ccol * 128 + kof;
#pragma unroll
    for (int kk = 0; kk < 4; ++kk) {
      bf16x8 bfr = *reinterpret_cast<const bf16x8*>(bp + kk * 32);
      acc[ct] = __builtin_amdgcn_mfma_f32_16x16x32_bf16(af[kk], bfr, acc[ct], 0, 0, 0);
    }
  }

  float s[4] = {0.f, 0.f, 0.f, 0.f}, q[4] = {0.f, 0.f, 0.f, 0.f};
#pragma unroll
  for (int ct = 0; ct < 4; ++ct) {
    const float bc = b[ch * 64 + ct * 16 + (l & 15)];
#pragma unroll
    for (int j = 0; j < 4; ++j) {
      float v = acc[ct][j] + bc;
      acc[ct][j] = v;
      s[j] += v;
      q[j] += v * v;
    }
  }
#pragma unroll
  for (int j = 0; j < 4; ++j) {
#pragma unroll
    for (int off = 1; off < 16; off <<= 1) {
      s[j] += __shfl_xor(s[j], off);
      q[j] += __shfl_xor(q[j], off);
    }
  }
  const int grp = l >> 4;
  if ((l & 15) == 0) {
#pragma unroll
    for (int j = 0; j < 4; ++j) {
      sS[rt][ch][grp * 4 + j] = s[j];
      sQ[rt][ch][grp * 4 + j] = q[j];
    }
  }
  __syncthreads();

#pragma unroll
  for (int j = 0; j < 4; ++j) {
    const int r = grp * 4 + j;
    const int row = rbase + rt * 16 + r;
    float S = sS[rt][0][r] + sS[rt][1][r];
    float Q = sQ[rt][0][r] + sQ[rt][1][r];
    float mu = S * (1.f / 128.f);
    float rstd = rsqrtf(fmaxf(Q * (1.f / 128.f) - mu * mu, 0.f) + LN_EPS);
    float nof = sNo[rt * 16 + r];
    if (row < N) {
#pragma unroll
      for (int ct = 0; ct < 4; ++ct) {
        const int ccol = ch * 64 + ct * 16 + (l & 15);
        float y = (acc[ct][j] - mu) * rstd * g[ccol] + be[ccol];
        y = fmaxf(y, 0.f) * nof;
        out[(size_t)row * 128 + ccol] = f2bf(y);
      }
    }
  }
}

// ============ final MFMA matmul [N,128]x[128,64] + bias -> f32 out ========
__global__ __launch_bounds__(256) void mm_final_mfma(
    const unsigned short* __restrict__ A, const unsigned short* __restrict__ Wt,
    const float* __restrict__ b, float* __restrict__ out, int N) {
  const int rbase = blockIdx.x * 32;
  const int w = threadIdx.x >> 6;
  const int l = threadIdx.x & 63;
  const int rt = w & 1, ch = w >> 1;
  const int arow = min(rbase + rt * 16 + (l & 15), N - 1);
  const int kof = (l >> 4) * 8;

  bf16x8 af[4];
  const unsigned short* ap = A + (size_t)arow * 128 + kof;
#pragma unroll
  for (int kk = 0; kk < 4; ++kk)
    af[kk] = *reinterpret_cast<const bf16x8*>(ap + kk * 32);

  f32x4 acc[2] = {};
#pragma unroll
  for (int ct = 0; ct < 2; ++ct) {
    const int ccol = ch * 32 + ct * 16 + (l & 15);
    const unsigned short* bp = Wt + (size_t)ccol * 128 + kof;
#pragma unroll
    for (int kk = 0; kk < 4; ++kk) {
      bf16x8 bfr = *reinterpret_cast<const bf16x8*>(bp + kk * 32);
      acc[ct] = __builtin_amdgcn_mfma_f32_16x16x32_bf16(af[kk], bfr, acc[ct], 0, 0, 0);
    }
  }
  const int grp = l >> 4;
#pragma unroll
  for (int ct = 0; ct < 2; ++ct) {
    const int ccol = ch * 32 + ct * 16 + (l & 15);
    const float bc = b[ccol];
#pragma unroll
    for (int j = 0; j < 4; ++j) {
      const int row = rbase + rt * 16 + grp * 4 + j;
      if (row < N) out[(size_t)row * 64 + ccol] = acc[ct][j] + bc;
    }
  }
}

extern "C" void kernel_launch(void* const* d_in, const int* in_sizes, int n_in,
                              void* d_out, int out_size, void* d_ws, size_t ws_size,
                              hipStream_t stream) {
  const float* feats = (const float*)d_in[0];
  const int*   src   = (const int*)d_in[1];
  const int*   dst   = (const int*)d_in[2];
  const float* W0    = (const float*)d_in[3];
  const float* b0    = (const float*)d_in[4];
  const float* g0    = (const float*)d_in[5];
  const float* be0   = (const float*)d_in[6];
  const float* W1    = (const float*)d_in[7];
  const float* b1    = (const float*)d_in[8];
  const float* g1    = (const float*)d_in[9];
  const float* be1   = (const float*)d_in[10];
  const float* W2    = (const float*)d_in[11];
  const float* b2    = (const float*)d_in[12];
  float* out = (float*)d_out;

  const int n = in_sizes[0] / 128;  // 100000
  const int e = in_sizes[1];        // 1600000

  float* ws = (float*)d_ws;
  auto pad4 = [](size_t x) { return (x + 3) & ~(size_t)3; };
  size_t o = 0;
  float* norm_o  = ws + o; o = pad4(o + n);
  float* norm_i  = ws + o; o = pad4(o + n);
  int*   dgo     = (int*)(ws + o); o = pad4(o + n);
  int*   dgi     = (int*)(ws + o); o = pad4(o + n);
  int*   row_st  = (int*)(ws + o); o = pad4(o + n + 1);
  int*   cursor  = (int*)(ws + o); o = pad4(o + n);
  int*   partial = (int*)(ws + o); o = pad4(o + 256);
  int*   offsets = (int*)(ws + o); o = pad4(o + 256);
  int*   edg_src = (int*)(ws + o); o = pad4(o + (size_t)e);
  unsigned short* featB = (unsigned short*)(ws + o); o = pad4(o + (size_t)n * 64);
  unsigned short* aggB  = (unsigned short*)(ws + o); o = pad4(o + (size_t)n * 64);
  unsigned short* hB    = (unsigned short*)(ws + o); o = pad4(o + (size_t)n * 64);
  unsigned short* Wt0   = (unsigned short*)(ws + o); o = pad4(o + 128 * 128 / 2);
  unsigned short* Wt1   = (unsigned short*)(ws + o); o = pad4(o + 128 * 128 / 2);
  unsigned short* Wt2   = (unsigned short*)(ws + o); o = pad4(o + 128 * 64 / 2);

  // ---- CSR build ----
  hipMemsetAsync(dgo, 0, 2 * (size_t)pad4(n) * sizeof(int), stream);
  deg_int_kernel<<<2048, 256, 0, stream>>>(src, dst, dgo, dgi, e);
  norm_from_int_kernel<<<(n + 255) / 256, 256, 0, stream>>>(dgo, dgi, norm_o, norm_i, n);
  scan_phaseA<<<256, 256, 0, stream>>>(dgi, partial, n);
  scan_phaseB<<<1, 256, 0, stream>>>(partial, offsets);
  scan_phaseC<<<256, 256, 0, stream>>>(dgi, offsets, row_st, n, e);
  hipMemsetAsync(cursor, 0, (size_t)n * sizeof(int), stream);
  fill_kernel<<<2048, 256, 0, stream>>>(src, dst, row_st, cursor, edg_src, e);

  // ---- weights -> bf16 transposed; feats -> bf16 with no-fold ----
  wconv_kernel<<<(128 * 128 + 255) / 256, 256, 0, stream>>>(W0, Wt0, 128, 128);
  wconv_kernel<<<(128 * 128 + 255) / 256, 256, 0, stream>>>(W1, Wt1, 128, 128);
  wconv_kernel<<<(128 * 64 + 255) / 256, 256, 0, stream>>>(W2, Wt2, 128, 64);
  featconv_kernel<<<(n + 7) / 8, 256, 0, stream>>>(feats, norm_o, featB, n);

  const int gblocks = (n + 3) / 4;
  const int mblocks = (n + 31) / 32;

  // layer 0
  gather_agg_b<<<gblocks, 256, 0, stream>>>(featB, row_st, edg_src, norm_i, aggB, n);
  mm_mfma_ln<<<mblocks, 256, 0, stream>>>(aggB, Wt0, b0, g0, be0, norm_o, hB, n);
  // layer 1
  gather_agg_b<<<gblocks, 256, 0, stream>>>(hB, row_st, edg_src, norm_i, aggB, n);
  mm_mfma_ln<<<mblocks, 256, 0, stream>>>(aggB, Wt1, b1, g1, be1, norm_o, hB, n);
  // final layer
  gather_agg_b<<<gblocks, 256, 0, stream>>>(hB, row_st, edg_src, norm_i, aggB, n);
  mm_final_mfma<<<mblocks, 256, 0, stream>>>(aggB, Wt2, b2, out, n);
}